// Round 2
// baseline (228.069 us; speedup 1.0000x reference)
//
#include <hip/hip_runtime.h>
#include <hip/hip_bf16.h>
#include <cstdint>

// Problem constants
#define Bb  8
#define Tt  2048
#define Cc  256
#define FDd 256
#define Kk  128
#define Vv  256
#define BT  (Bb * Tt)
#define NTRI 136          // 16*17/2 lower-triangular 128x128 blocks per batch

#define INV_SQRT_K 0.08838834764831845f  // 1/sqrt(128)

typedef __bf16 bf16x8 __attribute__((ext_vector_type(8)));
typedef __bf16 bf16x4 __attribute__((ext_vector_type(4)));
typedef float  f32x4  __attribute__((ext_vector_type(4)));

// async global->LDS, 16B per lane. LDS dest = wave-uniform base + lane*16.
__device__ __forceinline__ void gload16(const void* g, void* l) {
  __builtin_amdgcn_global_load_lds(
      (const __attribute__((address_space(1))) void*)g,
      (__attribute__((address_space(3))) void*)l, 16, 0, 0);
}

// ---------------------------------------------------------------------------
// prepw: fused prep + wprep (unchanged).
// ---------------------------------------------------------------------------
__global__ __launch_bounds__(256) void prepw_kernel(
    const float4* __restrict__ inp4, const float4* __restrict__ feat4,
    float4* __restrict__ out4, bf16x4* __restrict__ inpB4,
    bf16x4* __restrict__ featB4,
    const float* __restrict__ Wq, const float* __restrict__ Wk,
    const float* __restrict__ Wv, __bf16* __restrict__ Wqt,
    __bf16* __restrict__ Wkt, __bf16* __restrict__ Wvt)
{
  if (blockIdx.x < 4096) {
    const int g = blockIdx.x * 256 + threadIdx.x;   // 0 .. BT*64
    const int row = g >> 6, c = g & 63;
    const float4 x = inp4[g];
    out4[(size_t)row * 128 + c] = x;
    bf16x4 xb; xb[0] = (__bf16)x.x; xb[1] = (__bf16)x.y; xb[2] = (__bf16)x.z; xb[3] = (__bf16)x.w;
    inpB4[g] = xb;
    const float4 f = feat4[g];
    bf16x4 fb; fb[0] = (__bf16)f.x; fb[1] = (__bf16)f.y; fb[2] = (__bf16)f.z; fb[3] = (__bf16)f.w;
    featB4[g] = fb;
  } else {
    const int g = (blockIdx.x - 4096) * 256 + threadIdx.x;
    if (g < 65536) {                       // Wq: 512x128 -> Wqt 128x512
      const int n = g >> 9, k = g & 511;
      Wqt[g] = (__bf16)Wq[k * 128 + n];
    } else if (g < 98304) {                // Wk: 256x128 -> Wkt 128x256
      const int h = g - 65536;
      const int n = h >> 8, k = h & 255;
      Wkt[h] = (__bf16)Wk[k * 128 + n];
    } else {                               // Wv: 256x256 -> Wvt 256x256
      const int h = g - 98304;
      const int n = h >> 8, k = h & 255;
      Wvt[h] = (__bf16)Wv[k * 256 + n];
    }
  }
}

// ---------------------------------------------------------------------------
// qkv v2 (m97-style LDS tiles): one 128x128 output block per workgroup.
//   (unchanged — validated)
// ---------------------------------------------------------------------------
__global__ __launch_bounds__(256, 3) void qkv_mfma_kernel(
    const __bf16* __restrict__ inpB, const __bf16* __restrict__ featB,
    const __bf16* __restrict__ Wqt, const __bf16* __restrict__ Wkt,
    const __bf16* __restrict__ Wvt,
    const float* __restrict__ bq, const float* __restrict__ bk,
    const float* __restrict__ bv,
    __bf16* __restrict__ qb, __bf16* __restrict__ kb, __bf16* __restrict__ vT)
{
  __shared__ __bf16 Atile[128 * 64];
  __shared__ __bf16 Btile[128 * 64];
  const int panel = blockIdx.y;
  const int m0 = blockIdx.x * 128;
  const int lane = threadIdx.x & 63, wave = threadIdx.x >> 6;
  const int cl = lane & 15, quad = lane >> 4;
  const int jl0 = (wave >> 1) * 64;    // wave m-offset in tile
  const int vl0 = (wave & 1) * 64;     // wave n-offset in tile

  const __bf16* Wt; const float* bias; int kblocks;
  if (panel == 0)      { Wt = Wqt; bias = bq; kblocks = 8; }
  else if (panel == 1) { Wt = Wkt; bias = bk; kblocks = 4; }
  else                 { Wt = Wvt + (size_t)(panel - 2) * 128 * 256;
                         bias = bv + (panel - 2) * 128; kblocks = 4; }
  const int Kd = kblocks * 64;

  const int lrow = lane >> 3;
  const int lchunk = ((lane & 7) ^ lrow) * 8;      // element offset of 16B chunk

  f32x4 acc[4][4];
#pragma unroll
  for (int mt = 0; mt < 4; ++mt)
#pragma unroll
    for (int nt = 0; nt < 4; ++nt) acc[mt][nt] = (f32x4){0.f, 0.f, 0.f, 0.f};

  for (int kb = 0; kb < kblocks; ++kb) {
    const __bf16* Asrc = (panel == 0 && kb >= 4) ? featB : inpB;
    const int koff = (panel == 0 && kb >= 4) ? (kb - 4) * 64 : kb * 64;
    __syncthreads();                   // prior compute done before overwrite
#pragma unroll
    for (int t = 0; t < 4; ++t) {
      const int r0 = wave * 32 + t * 8;
      gload16(Asrc + (size_t)(m0 + r0 + lrow) * 256 + koff + lchunk, Atile + r0 * 64);
      gload16(Wt + (size_t)(r0 + lrow) * Kd + kb * 64 + lchunk, Btile + r0 * 64);
    }
    __syncthreads();                   // waitcnt vmcnt(0) + barrier
#pragma unroll
    for (int ks = 0; ks < 2; ++ks) {
      bf16x8 af[4], bfr[4];
#pragma unroll
      for (int mt = 0; mt < 4; ++mt) {
        const int jlr = jl0 + mt * 16 + cl;
        af[mt] = *(const bf16x8*)(Atile + jlr * 64 + (((ks * 4 + quad) ^ (jlr & 7)) * 8));
      }
#pragma unroll
      for (int nt = 0; nt < 4; ++nt) {
        const int vlr = vl0 + nt * 16 + cl;
        bfr[nt] = *(const bf16x8*)(Btile + vlr * 64 + (((ks * 4 + quad) ^ (vlr & 7)) * 8));
      }
#pragma unroll
      for (int mt = 0; mt < 4; ++mt)
#pragma unroll
        for (int nt = 0; nt < 4; ++nt)
          acc[mt][nt] = __builtin_amdgcn_mfma_f32_16x16x32_bf16(af[mt], bfr[nt], acc[mt][nt], 0, 0, 0);
    }
  }

  if (panel < 2) {
    __bf16* dst = (panel == 0) ? qb : kb;
    const float scale = (panel == 0) ? INV_SQRT_K : 1.0f;
#pragma unroll
    for (int mt = 0; mt < 4; ++mt) {
      const int row = m0 + jl0 + mt * 16 + quad * 4;
#pragma unroll
      for (int nt = 0; nt < 4; ++nt) {
        const int col = vl0 + nt * 16 + cl;
        const float bs = bias[col];
#pragma unroll
        for (int r = 0; r < 4; ++r)
          dst[(size_t)(row + r) * Kk + col] = (__bf16)((acc[mt][nt][r] + bs) * scale);
      }
    }
  } else {
    const int b = m0 >> 11;            // 128-row blocks never straddle a batch
#pragma unroll
    for (int mt = 0; mt < 4; ++mt) {
      const int t0 = (m0 & (Tt - 1)) + jl0 + mt * 16 + quad * 4;
#pragma unroll
      for (int nt = 0; nt < 4; ++nt) {
        const int vcol = (panel - 2) * 128 + vl0 + nt * 16 + cl;
        const float bs = bias[vl0 + nt * 16 + cl];
        bf16x4 v4;
#pragma unroll
        for (int r = 0; r < 4; ++r) v4[r] = (__bf16)(acc[mt][nt][r] + bs);
        *(bf16x4*)(vT + (size_t)(b * Vv + vcol) * Tt + t0) = v4;
      }
    }
  }
}

// ---------------------------------------------------------------------------
// sd: partialD only (no expS store). Direct register fragment loads from
//   qb/kb (16B contiguous per row, L1/L2-hot) — no LDS tiles, no staging
//   barriers. Per (b, lower-tri 128x128 block): QK^T MFMA, masked exp,
//   raw-fp32 column sums -> partialD[b][jt][i].
// ---------------------------------------------------------------------------
__global__ __launch_bounds__(256, 2) void sd_kernel(
    const __bf16* __restrict__ qb, const __bf16* __restrict__ kbuf,
    float* __restrict__ partialD)
{
  __shared__ float lcs[4][64];
  const int b = blockIdx.y, l = blockIdx.x;
  int jt = 0, base = 0;
  while (base + jt + 1 <= l) { base += jt + 1; ++jt; }   // uniform, <=16 iters
  const int it = l - base;

  const int lane = threadIdx.x & 63, wave = threadIdx.x >> 6;
  const int cl = lane & 15, quad = lane >> 4;
  const int jl0 = (wave >> 1) * 64;
  const int il0 = (wave & 1) * 64;
  const size_t rowbase = (size_t)b * Tt;
  const __bf16* qsrc = qb + (rowbase + jt * 128) * Kk;
  const __bf16* ksrc = kbuf + (rowbase + it * 128) * Kk;

  f32x4 acc[4][4];
#pragma unroll
  for (int mt = 0; mt < 4; ++mt)
#pragma unroll
    for (int nt = 0; nt < 4; ++nt) acc[mt][nt] = (f32x4){0.f, 0.f, 0.f, 0.f};

#pragma unroll
  for (int s = 0; s < 4; ++s) {
    bf16x8 af[4], bfr[4];
#pragma unroll
    for (int mt = 0; mt < 4; ++mt)
      af[mt] = *(const bf16x8*)(qsrc + (size_t)(jl0 + mt * 16 + cl) * Kk + (s * 4 + quad) * 8);
#pragma unroll
    for (int nt = 0; nt < 4; ++nt)
      bfr[nt] = *(const bf16x8*)(ksrc + (size_t)(il0 + nt * 16 + cl) * Kk + (s * 4 + quad) * 8);
#pragma unroll
    for (int mt = 0; mt < 4; ++mt)
#pragma unroll
      for (int nt = 0; nt < 4; ++nt)
        acc[mt][nt] = __builtin_amdgcn_mfma_f32_16x16x32_bf16(af[mt], bfr[nt], acc[mt][nt], 0, 0, 0);
  }

  // masked exp + raw fp32 column sums
  const bool diag = (it == jt);
  float cs[4] = {0.f, 0.f, 0.f, 0.f};
#pragma unroll
  for (int mt = 0; mt < 4; ++mt) {
    const int jl = jl0 + mt * 16 + quad * 4;
#pragma unroll
    for (int nt = 0; nt < 4; ++nt) {
      const int il = il0 + nt * 16 + cl;
#pragma unroll
      for (int r = 0; r < 4; ++r) {
        float p = __expf(acc[mt][nt][r]);
        if (diag && il > (jl + r)) p = 0.f;   // mask i > j (same-tile coords)
        cs[nt] += p;
      }
    }
  }
#pragma unroll
  for (int nt = 0; nt < 4; ++nt) {
    cs[nt] += __shfl_xor(cs[nt], 16);
    cs[nt] += __shfl_xor(cs[nt], 32);
  }
  if (quad == 0) {
#pragma unroll
    for (int nt = 0; nt < 4; ++nt) lcs[wave][nt * 16 + cl] = cs[nt];
  }
  __syncthreads();

  const int tid = threadIdx.x;
  if (tid < 128) {                      // block column c = tid
    const int w0 = (tid < 64) ? 0 : 1;  // waves {0,2} cols [0,64), {1,3} [64,128)
    const int lc = tid & 63;
    const float s = lcs[w0][lc] + lcs[w0 + 2][lc];
    partialD[((size_t)b * 16 + jt) * Tt + it * 128 + tid] = s;
  }
}

// ---------------------------------------------------------------------------
// pv: fused flash-style pass 2. Grid (32 j-tiles x 8 b), 512 thr = 8 waves
//   (2 j-halves x 4 v-quarters). Per block: recipD for needed i-cols (LDS),
//   Q-frags hoisted to regs; per 128-i-block: recompute QK^T (direct K-frag
//   loads), exp * recipD -> bf16 P in swizzled LDS, PV MFMA (direct V-frag
//   loads from vT). No expS, no vscale, 2 barriers/step, no vmcnt drains.
// ---------------------------------------------------------------------------
__global__ __launch_bounds__(512, 2) void pv_kernel(
    const __bf16* __restrict__ qb, const __bf16* __restrict__ kbuf,
    const __bf16* __restrict__ vT, const float* __restrict__ partialD,
    float* __restrict__ out)
{
  __shared__ __bf16 Pt[64 * 128];       // bf16 P tile, chunk-XOR-swizzled
  __shared__ float rcp[2048];
  const int b = blockIdx.y;
  const int jt = 31 - (int)blockIdx.x;  // 64-row j-tile
  const int j0 = jt * 64;
  const int nk = (j0 >> 7) + 1;         // i-blocks of 128 (1..16)
  const int tid = (int)threadIdx.x;
  const int lane = tid & 63, wave = tid >> 6;
  const int cl = lane & 15, quad = lane >> 4;
  const int wj = wave >> 2;             // j-half (32 rows)
  const int wi = wave & 3;              // QK i-quarter / PV v-quarter

  // recipD for i in [0, nk*128)
  for (int i = tid; i < nk * 128; i += 512) {
    float s = 0.f;
#pragma unroll
    for (int t = 0; t < 16; ++t) s += partialD[((size_t)b * 16 + t) * Tt + i];
    rcp[i] = 1.0f / s;
  }

  const size_t rowbase = (size_t)b * Tt;
  // Q fragments hoisted (rows j0 + wj*32 + mt*16 + cl), reused every step
  bf16x8 aq[2][4];
#pragma unroll
  for (int mt = 0; mt < 2; ++mt) {
    const __bf16* qrow = qb + (rowbase + j0 + wj * 32 + mt * 16 + cl) * Kk;
#pragma unroll
    for (int s = 0; s < 4; ++s)
      aq[mt][s] = *(const bf16x8*)(qrow + (s * 4 + quad) * 8);
  }

  f32x4 accv[2][4];
#pragma unroll
  for (int mt = 0; mt < 2; ++mt)
#pragma unroll
    for (int nt = 0; nt < 4; ++nt) accv[mt][nt] = (f32x4){0.f, 0.f, 0.f, 0.f};

  __syncthreads();                      // rcp ready

  const int d0 = j0 & 127;              // j0 - i0 on the diagonal block
  for (int kbI = 0; kbI < nk; ++kbI) {
    const int i0 = kbI * 128;
    // ---- QK^T: acc_qk[2][2] over K=128 (bit-identical to sd's s-loop) ----
    f32x4 aqk[2][2];
#pragma unroll
    for (int mt = 0; mt < 2; ++mt)
#pragma unroll
      for (int nt = 0; nt < 2; ++nt) aqk[mt][nt] = (f32x4){0.f, 0.f, 0.f, 0.f};
#pragma unroll
    for (int s = 0; s < 4; ++s) {
      bf16x8 bk2[2];
#pragma unroll
      for (int nt = 0; nt < 2; ++nt)
        bk2[nt] = *(const bf16x8*)(kbuf + (rowbase + i0 + wi * 32 + nt * 16 + cl) * Kk + (s * 4 + quad) * 8);
#pragma unroll
      for (int mt = 0; mt < 2; ++mt)
#pragma unroll
        for (int nt = 0; nt < 2; ++nt)
          aqk[mt][nt] = __builtin_amdgcn_mfma_f32_16x16x32_bf16(aq[mt][s], bk2[nt], aqk[mt][nt], 0, 0, 0);
    }
    __syncthreads();                    // prev PV finished reading Pt
    // ---- exp * recipD -> bf16 Pt (masked on diagonal block) ----
    const bool diag = (kbI == nk - 1);
#pragma unroll
    for (int mt = 0; mt < 2; ++mt) {
      const int jlb = wj * 32 + mt * 16 + quad * 4;
#pragma unroll
      for (int nt = 0; nt < 2; ++nt) {
        const int il = wi * 32 + nt * 16 + cl;
        const float r = rcp[i0 + il];
#pragma unroll
        for (int rr = 0; rr < 4; ++rr) {
          float p = __expf(aqk[mt][nt][rr]);
          if (diag && il > jlb + rr + d0) p = 0.f;   // mask i > j
          const int jl = jlb + rr;
          Pt[jl * 128 + ((((il >> 3) ^ (jl & 7)) << 3) | (il & 7))] = (__bf16)(p * r);
        }
      }
    }
    __syncthreads();                    // Pt ready
    // ---- PV: accv += P @ V  (direct V-frag loads from vT[v][i]) ----
#pragma unroll
    for (int s = 0; s < 4; ++s) {
      bf16x8 ap[2], bv4[4];
#pragma unroll
      for (int mt = 0; mt < 2; ++mt) {
        const int jlr = wj * 32 + mt * 16 + cl;
        ap[mt] = *(const bf16x8*)(Pt + jlr * 128 + (((s * 4 + quad) ^ (jlr & 7)) * 8));
      }
#pragma unroll
      for (int nt = 0; nt < 4; ++nt)
        bv4[nt] = *(const bf16x8*)(vT + ((size_t)b * Vv + wi * 64 + nt * 16 + cl) * Tt + i0 + (s * 4 + quad) * 8);
#pragma unroll
      for (int mt = 0; mt < 2; ++mt)
#pragma unroll
        for (int nt = 0; nt < 4; ++nt)
          accv[mt][nt] = __builtin_amdgcn_mfma_f32_16x16x32_bf16(ap[mt], bv4[nt], accv[mt][nt], 0, 0, 0);
    }
  }

  // ---- epilogue: fp32 stores to out[:, 256:512] ----
  float* obase = out + ((size_t)b * Tt + j0 + wj * 32) * (size_t)(Cc + Vv) + Cc + wi * 64;
#pragma unroll
  for (int mt = 0; mt < 2; ++mt)
#pragma unroll
    for (int nt = 0; nt < 4; ++nt)
#pragma unroll
      for (int rr = 0; rr < 4; ++rr)
        obase[(size_t)(mt * 16 + quad * 4 + rr) * (Cc + Vv) + nt * 16 + cl] = accv[mt][nt][rr];
}

// ---------------------------------------------------------------------------
extern "C" void kernel_launch(void* const* d_in, const int* in_sizes, int n_in,
                              void* d_out, int out_size, void* d_ws, size_t ws_size,
                              hipStream_t stream) {
  const float* inp  = (const float*)d_in[0];
  const float* feat = (const float*)d_in[1];
  const float* Wq   = (const float*)d_in[2];
  const float* bq   = (const float*)d_in[3];
  const float* Wk   = (const float*)d_in[4];
  const float* bk   = (const float*)d_in[5];
  const float* Wv   = (const float*)d_in[6];
  const float* bv   = (const float*)d_in[7];
  float* out = (float*)d_out;

  // ws layout (~35 MB):
  //  inpB 8M | featB 8M | qb 4M | kb 4M | vT 8M | Wqt/Wkt/Wvt 320K |
  //  partialD 2M @33M   (expS eliminated)
  char* ws = (char*)d_ws;
  __bf16* inpB   = (__bf16*)(ws);
  __bf16* featB  = (__bf16*)(ws + (8u << 20));
  __bf16* qb     = (__bf16*)(ws + (16u << 20));
  __bf16* kb     = (__bf16*)(ws + (20u << 20));
  __bf16* vT     = (__bf16*)(ws + (24u << 20));
  __bf16* Wqt    = (__bf16*)(ws + (32u << 20));
  __bf16* Wkt    = (__bf16*)(ws + (32u << 20) + (128u << 10));
  __bf16* Wvt    = (__bf16*)(ws + (32u << 20) + (192u << 10));
  float*  partialD = (float*)(ws + (33u << 20));

  prepw_kernel<<<dim3(4096 + 640), 256, 0, stream>>>(
      (const float4*)inp, (const float4*)feat, (float4*)out,
      (bf16x4*)inpB, (bf16x4*)featB, Wq, Wk, Wv, Wqt, Wkt, Wvt);
  qkv_mfma_kernel<<<dim3(BT / 128, 4), 256, 0, stream>>>(
      inpB, featB, Wqt, Wkt, Wvt, bq, bk, bv, qb, kb, vT);
  sd_kernel<<<dim3(NTRI, Bb), 256, 0, stream>>>(qb, kb, partialD);
  pv_kernel<<<dim3(32, Bb), 512, 0, stream>>>(qb, kb, vT, partialD, out);
}